// Round 7
// baseline (581.613 us; speedup 1.0000x reference)
//
#include <hip/hip_runtime.h>
#include <hip/hip_fp16.h>

// ---------------------------------------------------------------------------
// VGAE encoder, gather-form, fp16 table, quad-fused GEMM epilogue.
//   a[i] = dis_i*(g[i] + sum g[src_e]),  g = fp16(dis (.) h)
//   Each node is owned by a 4-lane quad; after the gather loop the quad
//   exchanges its 32-dim row via width-4 shuffles and applies the dense
//   layer from an LDS-resident W — no post-gather barrier, no row LDS
//   (R5's occupancy trap avoided). Layers write the next fp16 g directly.
//   Preprocessing: capacity-padded bucket scatter + per-bucket finalize.
// ---------------------------------------------------------------------------

#define BK_BITS 9
#define BK      (1 << BK_BITS)     // 512 dst nodes per bucket
#define BMASK   (BK - 1)
#define EPT     16
#define CHUNK   (256 * EPT)        // 4096 edges per block
#define CAP     16384              // bucket capacity (mean 8192, max ~8.6k)

// ---- pass A: scatter edges into capacity-padded dst-buckets ----------------
// ebuf[b*CAP + off] = (src << BK_BITS) | (dst & BMASK)
__global__ void k_bucket(const int* __restrict__ src, const int* __restrict__ dst,
                         int* __restrict__ bcur, int* __restrict__ ebuf, int E) {
    __shared__ int lcnt[256];
    __shared__ int lbase[256];
    int t = threadIdx.x;
    lcnt[t] = 0;
    __syncthreads();
    int e0 = blockIdx.x * CHUNK;
    int pk[EPT];
#pragma unroll
    for (int i = 0; i < EPT; ++i) {
        int e = e0 + i * 256 + t;
        pk[i] = -1;
        if (e < E) {
            int d = dst[e];
            int b = d >> BK_BITS;
            int off = atomicAdd(&lcnt[b], 1);          // off < CHUNK = 4096
            pk[i] = (b << 21) | (off << BK_BITS) | (d & BMASK);
        }
    }
    __syncthreads();
    lbase[t] = t * CAP + atomicAdd(&bcur[t], lcnt[t]);
    __syncthreads();
#pragma unroll
    for (int i = 0; i < EPT; ++i) {
        int e = e0 + i * 256 + t;
        if (e < E) {
            int b   = pk[i] >> 21;
            int off = (pk[i] >> BK_BITS) & 4095;
            int dl  = pk[i] & BMASK;
            int pos = lbase[b] + off;
            if (pos < (b + 1) * CAP)                  // overflow guard (never hit)
                ebuf[pos] = (src[e] << BK_BITS) | dl;
        }
    }
}

// ---- pass B: per-bucket finalize: starts, dis, sorted src, g0 --------------
__global__ void k_finalize(const int* __restrict__ bcur, int* __restrict__ starts,
                           float* __restrict__ dis, const int* __restrict__ ebuf,
                           int* __restrict__ es, const float* __restrict__ x,
                           __half* __restrict__ g0, int n, int E) {
    __shared__ int   hist[BK];
    __shared__ int   sc[BK];
    __shared__ int   sb[256];
    __shared__ float disL[BK];
    int b = blockIdx.x, t = threadIdx.x;
    if (t < 256) sb[t] = min(bcur[t], CAP);
    hist[t] = 0;
    __syncthreads();
    for (int o = 1; o < 256; o <<= 1) {
        int xv = 0;
        if (t < 256 && t >= o) xv = sb[t - o];
        __syncthreads();
        if (t < 256) sb[t] += xv;
        __syncthreads();
    }
    int cnt = min(bcur[b], CAP);
    int beg = sb[b] - cnt;                  // exclusive scan at b
    const int* eb = ebuf + (size_t)b * CAP;
    for (int j = t; j < cnt; j += BK)
        atomicAdd(&hist[eb[j] & BMASK], 1);
    __syncthreads();
    int cv = hist[t];
    sc[t] = cv;
    __syncthreads();
    for (int o = 1; o < BK; o <<= 1) {
        int xv = (t >= o) ? sc[t - o] : 0;
        __syncthreads();
        sc[t] += xv;
        __syncthreads();
    }
    int excl = sc[t] - cv;
    int gnode = (b << BK_BITS) + t;
    float dv = rsqrtf((float)cv + 1.0f);    // +1 = self loop
    disL[t] = dv;
    if (gnode < n) {
        starts[gnode] = beg + excl;
        dis[gnode] = dv;
    }
    if (b == 0 && t == 0) starts[n] = E;
    hist[t] = excl;                         // reuse as cursor
    __syncthreads();
    for (int j = t; j < cnt; j += BK) {
        int v = eb[j];
        int off = atomicAdd(&hist[v & BMASK], 1);
        es[beg + off] = v >> BK_BITS;
    }
    // g0 = fp16(dis (.) x) for this bucket's nodes (coalesced 8 B stores)
    int node0 = b << BK_BITS;
    const float4* x4 = (const float4*)x;
    uint2* g2 = (uint2*)g0;
    for (int idx = t; idx < BK * 8; idx += BK) {
        int r = idx >> 3, lane = idx & 7;
        int nd = node0 + r;
        if (nd < n) {
            float d = disL[r];
            float4 v = x4[(size_t)nd * 8 + lane];
            __half2 lo = __floats2half2_rn(d * v.x, d * v.y);
            __half2 hi = __floats2half2_rn(d * v.z, d * v.w);
            uint2 u;
            u.x = *(unsigned int*)&lo;
            u.y = *(unsigned int*)&hi;
            g2[(size_t)nd * 8 + lane] = u;
        }
    }
}

// ---- gather helper: accumulate 8 halves into fp32 --------------------------
__device__ inline void acc8(uint4 u, float* s) {
    __half2 h0 = *(__half2*)&u.x, h1 = *(__half2*)&u.y;
    __half2 h2 = *(__half2*)&u.z, h3 = *(__half2*)&u.w;
    float2 f0 = __half22float2(h0), f1 = __half22float2(h1);
    float2 f2 = __half22float2(h2), f3 = __half22float2(h3);
    s[0] += f0.x; s[1] += f0.y; s[2] += f1.x; s[3] += f1.y;
    s[4] += f2.x; s[5] += f2.y; s[6] += f3.x; s[7] += f3.y;
}

// ---- fused layer (32ch): gather -> quad-shuffle GEMM -> relu -> fp16 -------
// 256 threads = 64 nodes x 4 lanes; lane holds channels lane*8..lane*8+7
__global__ void k_layer32(const int* __restrict__ starts, const int* __restrict__ es,
                          const float* __restrict__ dis, const __half* __restrict__ g,
                          const float* __restrict__ W, const float* __restrict__ bias,
                          __half* __restrict__ gout, int n) {
    __shared__ float Ws[32][32];
    int t = threadIdx.x;
    ((float4*)Ws)[t] = ((const float4*)W)[t];   // 1024 floats
    __syncthreads();
    int node = blockIdx.x * 64 + (t >> 2);
    if (node >= n) return;
    int lane = t & 3;
    const uint4* g4 = (const uint4*)g;
    float s[8] = {0, 0, 0, 0, 0, 0, 0, 0};
    acc8(g4[(size_t)node * 4 + lane], s);       // self term
    int j = starts[node], end = starts[node + 1];
    for (; j + 3 < end; j += 4) {
        uint4 u0 = g4[(size_t)es[j] * 4 + lane];
        uint4 u1 = g4[(size_t)es[j + 1] * 4 + lane];
        uint4 u2 = g4[(size_t)es[j + 2] * 4 + lane];
        uint4 u3 = g4[(size_t)es[j + 3] * 4 + lane];
        acc8(u0, s); acc8(u1, s); acc8(u2, s); acc8(u3, s);
    }
    for (; j < end; ++j) acc8(g4[(size_t)es[j] * 4 + lane], s);
    float dd = dis[node];
#pragma unroll
    for (int i = 0; i < 8; ++i) s[i] *= dd;     // a-row fragment (channels lane*8+i)
    // quad-shuffle GEMM: acc[c0+i] = bias + sum_k a[k]*W[k][c0+i]
    int c0 = lane * 8;
    float4 bb0 = ((const float4*)bias)[lane * 2];
    float4 bb1 = ((const float4*)bias)[lane * 2 + 1];
    float acc[8] = {bb0.x, bb0.y, bb0.z, bb0.w, bb1.x, bb1.y, bb1.z, bb1.w};
#pragma unroll
    for (int q = 0; q < 4; ++q) {
        float av[8];
#pragma unroll
        for (int i = 0; i < 8; ++i) av[i] = __shfl(s[i], q, 4);
#pragma unroll
        for (int kk = 0; kk < 8; ++kk) {
            int k = q * 8 + kk;
            float rk = av[kk];
            float4 w0 = *(const float4*)&Ws[k][c0];
            float4 w1 = *(const float4*)&Ws[k][c0 + 4];
            acc[0] += rk * w0.x; acc[1] += rk * w0.y;
            acc[2] += rk * w0.z; acc[3] += rk * w0.w;
            acc[4] += rk * w1.x; acc[5] += rk * w1.y;
            acc[6] += rk * w1.z; acc[7] += rk * w1.w;
        }
    }
    __half2 h0 = __floats2half2_rn(dd * fmaxf(acc[0], 0.f), dd * fmaxf(acc[1], 0.f));
    __half2 h1 = __floats2half2_rn(dd * fmaxf(acc[2], 0.f), dd * fmaxf(acc[3], 0.f));
    __half2 h2 = __floats2half2_rn(dd * fmaxf(acc[4], 0.f), dd * fmaxf(acc[5], 0.f));
    __half2 h3 = __floats2half2_rn(dd * fmaxf(acc[6], 0.f), dd * fmaxf(acc[7], 0.f));
    uint4 u;
    u.x = *(unsigned int*)&h0; u.y = *(unsigned int*)&h1;
    u.z = *(unsigned int*)&h2; u.w = *(unsigned int*)&h3;
    ((uint4*)gout)[(size_t)node * 4 + lane] = u;
}

// ---- fused final layer (64ch out): gather -> quad GEMM -> mu|logvar --------
// lane computes 16 output channels c0 = lane*16
__global__ void k_layer64(const int* __restrict__ starts, const int* __restrict__ es,
                          const float* __restrict__ dis, const __half* __restrict__ g,
                          const float* __restrict__ Wmu, const float* __restrict__ Wlv,
                          const float* __restrict__ bmu, const float* __restrict__ blv,
                          float* __restrict__ out, int n) {
    __shared__ float Ws[32][64];
    int t = threadIdx.x;
    for (int i = t; i < 1024; i += 256) {
        int k = i >> 5, c = i & 31;
        Ws[k][c]      = Wmu[i];
        Ws[k][c + 32] = Wlv[i];
    }
    __syncthreads();
    int node = blockIdx.x * 64 + (t >> 2);
    if (node >= n) return;
    int lane = t & 3;
    const uint4* g4 = (const uint4*)g;
    float s[8] = {0, 0, 0, 0, 0, 0, 0, 0};
    acc8(g4[(size_t)node * 4 + lane], s);
    int j = starts[node], end = starts[node + 1];
    for (; j + 3 < end; j += 4) {
        uint4 u0 = g4[(size_t)es[j] * 4 + lane];
        uint4 u1 = g4[(size_t)es[j + 1] * 4 + lane];
        uint4 u2 = g4[(size_t)es[j + 2] * 4 + lane];
        uint4 u3 = g4[(size_t)es[j + 3] * 4 + lane];
        acc8(u0, s); acc8(u1, s); acc8(u2, s); acc8(u3, s);
    }
    for (; j < end; ++j) acc8(g4[(size_t)es[j] * 4 + lane], s);
    float dd = dis[node];
#pragma unroll
    for (int i = 0; i < 8; ++i) s[i] *= dd;
    int c0 = lane * 16;
    float acc[16];
#pragma unroll
    for (int i = 0; i < 16; ++i)
        acc[i] = (c0 < 32) ? bmu[c0 + i] : blv[c0 - 32 + i];
#pragma unroll
    for (int q = 0; q < 4; ++q) {
        float av[8];
#pragma unroll
        for (int i = 0; i < 8; ++i) av[i] = __shfl(s[i], q, 4);
#pragma unroll
        for (int kk = 0; kk < 8; ++kk) {
            int k = q * 8 + kk;
            float rk = av[kk];
#pragma unroll
            for (int i = 0; i < 16; i += 4) {
                float4 w = *(const float4*)&Ws[k][c0 + i];
                acc[i]     += rk * w.x;
                acc[i + 1] += rk * w.y;
                acc[i + 2] += rk * w.z;
                acc[i + 3] += rk * w.w;
            }
        }
    }
    float* dstp = (c0 < 32) ? (out + (size_t)node * 32 + c0)
                            : (out + (size_t)n * 32 + (size_t)node * 32 + (c0 - 32));
#pragma unroll
    for (int i = 0; i < 16; i += 4)
        *(float4*)(dstp + i) = make_float4(acc[i], acc[i + 1], acc[i + 2], acc[i + 3]);
}

// ---- launch ----------------------------------------------------------------

extern "C" void kernel_launch(void* const* d_in, const int* in_sizes, int n_in,
                              void* d_out, int out_size, void* d_ws, size_t ws_size,
                              hipStream_t stream) {
    const float* x   = (const float*)d_in[0];
    const int*   ei  = (const int*)d_in[1];
    const float* W1  = (const float*)d_in[2];
    const float* b1  = (const float*)d_in[3];
    const float* W2  = (const float*)d_in[4];
    const float* b2  = (const float*)d_in[5];
    const float* Wmu = (const float*)d_in[6];
    const float* bmu = (const float*)d_in[7];
    const float* Wlv = (const float*)d_in[8];
    const float* blv = (const float*)d_in[9];
    float* out = (float*)d_out;

    int n = in_sizes[0] / 32;   // 100000
    int E = in_sizes[1] / 2;    // 1600000
    const int* src = ei;
    const int* dst = ei + E;
    int nbuck = (n + BK - 1) >> BK_BITS;   // 196 (<= 256)

    // workspace layout (all segments 16B-aligned)
    int*    bcur   = (int*)d_ws;                   // 256
    int     npad   = (n + 4) & ~3;
    int*    starts = bcur + 256;                   // n+1 (padded)
    float*  dis    = (float*)(starts + npad);      // n
    int*    es     = (int*)(dis + n);              // E
    __half* gA     = (__half*)(es + E);            // n*32 fp16
    __half* gB     = gA + (size_t)n * 32;          // n*32 fp16
    int*    ebuf   = (int*)(gB + (size_t)n * 32);  // 256*CAP ints (~16.8M)

    int nblk = (E + CHUNK - 1) / CHUNK;
    int lgrid = (n + 63) / 64;

    // ---- edge preprocessing ----
    hipMemsetAsync(bcur, 0, 256 * sizeof(int), stream);
    k_bucket<<<nblk, 256, 0, stream>>>(src, dst, bcur, ebuf, E);
    k_finalize<<<nbuck, BK, 0, stream>>>(bcur, starts, dis, ebuf, es, x, gA, n, E);

    // ---- fused layers ----
    k_layer32<<<lgrid, 256, 0, stream>>>(starts, es, dis, gA, W1, b1, gB, n);
    k_layer32<<<lgrid, 256, 0, stream>>>(starts, es, dis, gB, W2, b2, gA, n);
    k_layer64<<<lgrid, 256, 0, stream>>>(starts, es, dis, gA, Wmu, Wlv, bmu, blv, out, n);
}

// Round 8
// 295.037 us; speedup vs baseline: 1.9713x; 1.9713x over previous
//
#include <hip/hip_runtime.h>
#include <hip/hip_fp16.h>

// ---------------------------------------------------------------------------
// VGAE encoder, gather-form, fp16 gather table, SPLIT kernels.
//   a[i] = dis_i*(g[i] + sum_{e:dst=i} g[src_e]),  g = fp16(dis (.) h)
//   Fusion of gather+GEMM regressed twice (R5: occupancy collapse; R7:
//   register spill -> 762 MB scratch traffic). Split kernels keep the
//   gather at 0 LDS / low VGPR / ~66% occupancy.
//   Preprocessing: capacity-padded bucket scatter + per-bucket finalize
//   (no separate histogram pass).
// ---------------------------------------------------------------------------

#define BK_BITS 9
#define BK      (1 << BK_BITS)     // 512 dst nodes per bucket
#define BMASK   (BK - 1)
#define EPT     16
#define CHUNK   (256 * EPT)        // 4096 edges per block
#define CAP     16384              // bucket capacity (mean 8192, max ~8.6k)

// ---- pass A: scatter edges into capacity-padded dst-buckets ----------------
// ebuf[b*CAP + off] = (src << BK_BITS) | (dst & BMASK)
__global__ void k_bucket(const int* __restrict__ src, const int* __restrict__ dst,
                         int* __restrict__ bcur, int* __restrict__ ebuf, int E) {
    __shared__ int lcnt[256];
    __shared__ int lbase[256];
    int t = threadIdx.x;
    lcnt[t] = 0;
    __syncthreads();
    int e0 = blockIdx.x * CHUNK;
    int pk[EPT];
#pragma unroll
    for (int i = 0; i < EPT; ++i) {
        int e = e0 + i * 256 + t;
        pk[i] = -1;
        if (e < E) {
            int d = dst[e];
            int b = d >> BK_BITS;
            int off = atomicAdd(&lcnt[b], 1);          // off < CHUNK = 4096
            pk[i] = (b << 21) | (off << BK_BITS) | (d & BMASK);
        }
    }
    __syncthreads();
    lbase[t] = t * CAP + atomicAdd(&bcur[t], lcnt[t]);
    __syncthreads();
#pragma unroll
    for (int i = 0; i < EPT; ++i) {
        int e = e0 + i * 256 + t;
        if (e < E) {
            int b   = pk[i] >> 21;
            int off = (pk[i] >> BK_BITS) & 4095;
            int dl  = pk[i] & BMASK;
            int pos = lbase[b] + off;
            if (pos < (b + 1) * CAP)                  // overflow guard (never hit)
                ebuf[pos] = (src[e] << BK_BITS) | dl;
        }
    }
}

// ---- pass B: per-bucket finalize: starts, dis, sorted src, g0 --------------
__global__ void k_finalize(const int* __restrict__ bcur, int* __restrict__ starts,
                           float* __restrict__ dis, const int* __restrict__ ebuf,
                           int* __restrict__ es, const float* __restrict__ x,
                           __half* __restrict__ g0, int n, int E) {
    __shared__ int   hist[BK];
    __shared__ int   sc[BK];
    __shared__ int   sb[256];
    __shared__ float disL[BK];
    int b = blockIdx.x, t = threadIdx.x;
    if (t < 256) sb[t] = min(bcur[t], CAP);
    hist[t] = 0;
    __syncthreads();
    for (int o = 1; o < 256; o <<= 1) {
        int xv = 0;
        if (t < 256 && t >= o) xv = sb[t - o];
        __syncthreads();
        if (t < 256) sb[t] += xv;
        __syncthreads();
    }
    int cnt = min(bcur[b], CAP);
    int beg = sb[b] - cnt;                  // exclusive scan at b
    const int* eb = ebuf + (size_t)b * CAP;
    for (int j = t; j < cnt; j += BK)
        atomicAdd(&hist[eb[j] & BMASK], 1);
    __syncthreads();
    int cv = hist[t];
    sc[t] = cv;
    __syncthreads();
    for (int o = 1; o < BK; o <<= 1) {
        int xv = (t >= o) ? sc[t - o] : 0;
        __syncthreads();
        sc[t] += xv;
        __syncthreads();
    }
    int excl = sc[t] - cv;
    int gnode = (b << BK_BITS) + t;
    float dv = rsqrtf((float)cv + 1.0f);    // +1 = self loop
    disL[t] = dv;
    if (gnode < n) {
        starts[gnode] = beg + excl;
        dis[gnode] = dv;
    }
    if (b == 0 && t == 0) starts[n] = E;
    hist[t] = excl;                         // reuse as cursor
    __syncthreads();
    for (int j = t; j < cnt; j += BK) {
        int v = eb[j];
        int off = atomicAdd(&hist[v & BMASK], 1);
        es[beg + off] = v >> BK_BITS;
    }
    // g0 = fp16(dis (.) x) for this bucket's nodes (coalesced 8 B stores)
    int node0 = b << BK_BITS;
    const float4* x4 = (const float4*)x;
    uint2* g2 = (uint2*)g0;
    for (int idx = t; idx < BK * 8; idx += BK) {
        int r = idx >> 3, lane = idx & 7;
        int nd = node0 + r;
        if (nd < n) {
            float d = disL[r];
            float4 v = x4[(size_t)nd * 8 + lane];
            __half2 lo = __floats2half2_rn(d * v.x, d * v.y);
            __half2 hi = __floats2half2_rn(d * v.z, d * v.w);
            uint2 u;
            u.x = *(unsigned int*)&lo;
            u.y = *(unsigned int*)&hi;
            g2[(size_t)nd * 8 + lane] = u;
        }
    }
}

// ---- gather helper: accumulate 8 halves into fp32 --------------------------
__device__ inline void acc8(uint4 u, float* s) {
    __half2 h0 = *(__half2*)&u.x, h1 = *(__half2*)&u.y;
    __half2 h2 = *(__half2*)&u.z, h3 = *(__half2*)&u.w;
    float2 f0 = __half22float2(h0), f1 = __half22float2(h1);
    float2 f2 = __half22float2(h2), f3 = __half22float2(h3);
    s[0] += f0.x; s[1] += f0.y; s[2] += f1.x; s[3] += f1.y;
    s[4] += f2.x; s[5] += f2.y; s[6] += f3.x; s[7] += f3.y;
}

// ---- aggregation: a[i] = dis_i*(g[i] + sum g[src_e]), fp32 accum -----------
// 4 lanes/node (16 B each); 256 threads = 64 nodes; vectorized es loads
__global__ void k_agg(const int* __restrict__ starts, const int* __restrict__ es,
                      const float* __restrict__ dis, const __half* __restrict__ g,
                      float* __restrict__ out, int n) {
    int t = threadIdx.x;
    int node = blockIdx.x * 64 + (t >> 2);
    if (node >= n) return;
    int lane = t & 3;
    const uint4* g4 = (const uint4*)g;     // 16 B = 8 halves
    float s[8] = {0, 0, 0, 0, 0, 0, 0, 0};
    acc8(g4[(size_t)node * 4 + lane], s);  // self term
    int j = starts[node], end = starts[node + 1];
    while (j < end && (j & 3)) {           // align to int4 boundary
        acc8(g4[(size_t)es[j] * 4 + lane], s);
        ++j;
    }
    for (; j + 8 <= end; j += 8) {         // 8 gathers in flight
        int4 e0 = *(const int4*)(es + j);
        int4 e1 = *(const int4*)(es + j + 4);
        uint4 u0 = g4[(size_t)e0.x * 4 + lane];
        uint4 u1 = g4[(size_t)e0.y * 4 + lane];
        uint4 u2 = g4[(size_t)e0.z * 4 + lane];
        uint4 u3 = g4[(size_t)e0.w * 4 + lane];
        uint4 u4 = g4[(size_t)e1.x * 4 + lane];
        uint4 u5 = g4[(size_t)e1.y * 4 + lane];
        uint4 u6 = g4[(size_t)e1.z * 4 + lane];
        uint4 u7 = g4[(size_t)e1.w * 4 + lane];
        acc8(u0, s); acc8(u1, s); acc8(u2, s); acc8(u3, s);
        acc8(u4, s); acc8(u5, s); acc8(u6, s); acc8(u7, s);
    }
    if (j + 4 <= end) {
        int4 e0 = *(const int4*)(es + j);
        uint4 u0 = g4[(size_t)e0.x * 4 + lane];
        uint4 u1 = g4[(size_t)e0.y * 4 + lane];
        uint4 u2 = g4[(size_t)e0.z * 4 + lane];
        uint4 u3 = g4[(size_t)e0.w * 4 + lane];
        acc8(u0, s); acc8(u1, s); acc8(u2, s); acc8(u3, s);
        j += 4;
    }
    for (; j < end; ++j) acc8(g4[(size_t)es[j] * 4 + lane], s);
    float dd = dis[node];
    float4 o0 = make_float4(dd * s[0], dd * s[1], dd * s[2], dd * s[3]);
    float4 o1 = make_float4(dd * s[4], dd * s[5], dd * s[6], dd * s[7]);
    float4* op = (float4*)out + (size_t)node * 8 + lane * 2;
    op[0] = o0;
    op[1] = o1;
}

// ---- dense layers ----------------------------------------------------------

// gout = fp16(dis (.) relu(in @ W + b)) ; 256 threads = 8 nodes x 32 channels
__global__ void k_gemm32(const float* __restrict__ in, const float* __restrict__ W,
                         const float* __restrict__ b, const float* __restrict__ dis,
                         __half* __restrict__ gout, int n) {
    __shared__ float Ws[32][33];
    __shared__ float Xs[8][33];
    int t = threadIdx.x;
    for (int i = t; i < 1024; i += 256) Ws[i >> 5][i & 31] = W[i];
    int r = t >> 5, c = t & 31;
    int node = blockIdx.x * 8 + r;
    Xs[r][c] = (node < n) ? in[node * 32 + c] : 0.f;
    __syncthreads();
    if (node >= n) return;
    float sum = b[c];
#pragma unroll
    for (int k = 0; k < 32; ++k) sum += Xs[r][k] * Ws[k][c];
    gout[(size_t)node * 32 + c] = __float2half_rn(dis[node] * fmaxf(sum, 0.f));
}

// mu = in@Wmu + bmu -> out[0:n*32] ; lv = in@Wlv + blv -> out[n*32:]
__global__ void k_gemm64(const float* __restrict__ in, const float* __restrict__ Wmu,
                         const float* __restrict__ Wlv, const float* __restrict__ bmu,
                         const float* __restrict__ blv, float* __restrict__ out, int n) {
    __shared__ float Ws[32][64];
    __shared__ float Xs[4][33];
    int t = threadIdx.x;
    for (int i = t; i < 1024; i += 256) {
        int k = i >> 5, c = i & 31;
        Ws[k][c]      = Wmu[i];
        Ws[k][c + 32] = Wlv[i];
    }
    if (t < 128) {
        int r = t >> 5, c = t & 31;
        int node = blockIdx.x * 4 + r;
        Xs[r][c] = (node < n) ? in[node * 32 + c] : 0.f;
    }
    __syncthreads();
    int r = t >> 6, c = t & 63;
    int node = blockIdx.x * 4 + r;
    if (node >= n) return;
    float sum = (c < 32) ? bmu[c] : blv[c - 32];
#pragma unroll
    for (int k = 0; k < 32; ++k) sum += Xs[r][k] * Ws[k][c];
    if (c < 32) out[(size_t)node * 32 + c] = sum;
    else        out[(size_t)n * 32 + (size_t)node * 32 + (c - 32)] = sum;
}

// ---- launch ----------------------------------------------------------------

extern "C" void kernel_launch(void* const* d_in, const int* in_sizes, int n_in,
                              void* d_out, int out_size, void* d_ws, size_t ws_size,
                              hipStream_t stream) {
    const float* x   = (const float*)d_in[0];
    const int*   ei  = (const int*)d_in[1];
    const float* W1  = (const float*)d_in[2];
    const float* b1  = (const float*)d_in[3];
    const float* W2  = (const float*)d_in[4];
    const float* b2  = (const float*)d_in[5];
    const float* Wmu = (const float*)d_in[6];
    const float* bmu = (const float*)d_in[7];
    const float* Wlv = (const float*)d_in[8];
    const float* blv = (const float*)d_in[9];
    float* out = (float*)d_out;

    int n = in_sizes[0] / 32;   // 100000
    int E = in_sizes[1] / 2;    // 1600000
    const int* src = ei;
    const int* dst = ei + E;
    int nbuck = (n + BK - 1) >> BK_BITS;   // 196 (<= 256)

    // workspace layout (all segments 16B-aligned)
    int*    bcur   = (int*)d_ws;                      // 256
    int     npad   = (n + 4) & ~3;
    int*    starts = bcur + 256;                      // n+1 (padded)
    float*  dis    = (float*)(starts + npad);         // n
    int*    es     = (int*)(dis + n);                 // E
    float*  a32    = (float*)(es + E);                // n*32 fp32
    __half* gA     = (__half*)(a32 + (size_t)n * 32); // n*32 fp16
    __half* gB     = gA + (size_t)n * 32;             // n*32 fp16
    int*    ebuf   = (int*)(gB + (size_t)n * 32);     // 256*CAP ints (16.8 MB)

    int nblk = (E + CHUNK - 1) / CHUNK;
    int agrid = (n + 63) / 64;

    // ---- edge preprocessing ----
    hipMemsetAsync(bcur, 0, 256 * sizeof(int), stream);
    k_bucket<<<nblk, 256, 0, stream>>>(src, dst, bcur, ebuf, E);
    k_finalize<<<nbuck, BK, 0, stream>>>(bcur, starts, dis, ebuf, es, x, gA, n, E);

    // ---- layer 1 ----
    k_agg<<<agrid, 256, 0, stream>>>(starts, es, dis, gA, a32, n);
    k_gemm32<<<(n + 7) / 8, 256, 0, stream>>>(a32, W1, b1, dis, gB, n);

    // ---- layer 2 ----
    k_agg<<<agrid, 256, 0, stream>>>(starts, es, dis, gB, a32, n);
    k_gemm32<<<(n + 7) / 8, 256, 0, stream>>>(a32, W2, b2, dis, gA, n);

    // ---- mu/logvar ----
    k_agg<<<agrid, 256, 0, stream>>>(starts, es, dis, gA, a32, n);
    k_gemm64<<<(n + 3) / 4, 256, 0, stream>>>(a32, Wmu, Wlv, bmu, blv, out, n);
}